// Round 17
// baseline (82.207 us; speedup 1.0000x reference)
//
#include <hip/hip_runtime.h>

#define NN 128   // modes

// ---- whole-wave lane shifts via DPP (wave_shl:1 / wave_shr:1), proven R9-R16 ----
__device__ __forceinline__ float wshl1(float x) {   // lane i <- lane i+1
    return __int_as_float(__builtin_amdgcn_update_dpp(
        __float_as_int(x), __float_as_int(x), 0x130, 0xf, 0xf, false));
}
__device__ __forceinline__ float wshr1(float x) {   // lane i <- lane i-1
    return __int_as_float(__builtin_amdgcn_update_dpp(
        __float_as_int(x), __float_as_int(x), 0x138, 0xf, 0xf, false));
}

// (cos,sin) pair for the lane's two even rows of one layer
__device__ __forceinline__ float4 make_cs(float2 th) {
    float s0, c0, s1, c1;
    __sincosf(th.x, &s0, &c0);
    __sincosf(th.y, &s1, &c1);
    return make_float4(c0, s0, c1, s1);
}

// ---- 127 layers J0..J0+126, R15 fused structure (static ring, dist-7, DPP) ----
// On exit returns cs(theta[J0+127]) (for J0=127: the fold coefficients).
template<int J0>
__device__ __forceinline__ float4 run127(const float2* __restrict__ TL, const int l,
                                         float2& v0, float2& v1, float2& v2, float2& v3)
{
    const float A  = sqrtf(0.95f * 0.505f);
    const float B  = sqrtf(0.95f * 0.495f);
    const float C2 = sqrtf(0.98f * 0.01f);
    const float S2 = sqrtf(0.98f * 0.99f);
    const float ec0 = (l == 0)  ? S2 : C2, es0 = (l == 0)  ? 0.f : S2;
    const float ec3 = (l == 63) ? S2 : C2, es3 = (l == 63) ? 0.f : S2;

    float2 t0 = TL[(J0+0)*64], t1 = TL[(J0+1)*64], t2 = TL[(J0+2)*64],
           t3 = TL[(J0+3)*64], t4 = TL[(J0+4)*64], t5 = TL[(J0+5)*64],
           t6 = TL[(J0+6)*64], t7 = TL[(J0+7)*64];

    auto layer = [&](float4 t) {
        float rx = t.x * v0.x - t.y * v0.y;     // e^{i th} * v0
        float ry = t.x * v0.y + t.y * v0.x;
        float qx = t.z * v2.x - t.w * v2.y;     // e^{i th'} * v2
        float qy = t.z * v2.y + t.w * v2.x;
        float2 n0, n1, n2, n3;
        n0.x = A * rx   - B * v1.y;  n0.y = A * ry   + B * v1.x;
        n1.x = A * v1.x - B * ry;    n1.y = A * v1.y + B * rx;
        n2.x = A * qx   - B * v3.y;  n2.y = A * qy   + B * v3.x;
        n3.x = A * v3.x - B * qy;    n3.y = A * v3.y + B * qx;
        v0 = n0; v1 = n1; v2 = n2; v3 = n3;
    };
    auto crossl = [&]() {
        float nx = wshl1(v0.x), ny = wshl1(v0.y);   // lane l+1's v0
        float px = wshr1(v3.x), py = wshr1(v3.y);   // lane l-1's v3
        float2 m0, m1, m2, m3;
        m0.x = ec0 * v0.x - es0 * py;  m0.y = ec0 * v0.y + es0 * px;
        m3.x = ec3 * v3.x - es3 * ny;  m3.y = ec3 * v3.y + es3 * nx;
        m1.x = C2 * v1.x - S2 * v2.y;  m1.y = C2 * v1.y + S2 * v2.x;
        m2.x = C2 * v2.x - S2 * v1.y;  m2.y = C2 * v2.y + S2 * v1.x;
        v0 = m0; v1 = m1; v2 = m2; v3 = m3;
    };

    float4 cf = make_cs(t0);   // layer J0 coefficients

    // 15 batches of 8: layers J0..J0+119. Max load index = J0+127 (<=254).
    for (int j8 = J0; j8 < J0 + 120; j8 += 8) {
        { t0 = TL[(j8+ 8)*64]; float4 cfn = make_cs(t1); layer(cf); if (((J0+0)&1)==0) crossl(); cf = cfn; }
        { t1 = TL[(j8+ 9)*64]; float4 cfn = make_cs(t2); layer(cf); if (((J0+1)&1)==0) crossl(); cf = cfn; }
        { t2 = TL[(j8+10)*64]; float4 cfn = make_cs(t3); layer(cf); if (((J0+2)&1)==0) crossl(); cf = cfn; }
        { t3 = TL[(j8+11)*64]; float4 cfn = make_cs(t4); layer(cf); if (((J0+3)&1)==0) crossl(); cf = cfn; }
        { t4 = TL[(j8+12)*64]; float4 cfn = make_cs(t5); layer(cf); if (((J0+4)&1)==0) crossl(); cf = cfn; }
        { t5 = TL[(j8+13)*64]; float4 cfn = make_cs(t6); layer(cf); if (((J0+5)&1)==0) crossl(); cf = cfn; }
        { t6 = TL[(j8+14)*64]; float4 cfn = make_cs(t7); layer(cf); if (((J0+6)&1)==0) crossl(); cf = cfn; }
        { t7 = TL[(j8+15)*64]; float4 cfn = make_cs(t0); layer(cf); if (((J0+7)&1)==0) crossl(); cf = cfn; }
    }
    // tail: layers J0+120..J0+126 (7 layers)
    { float4 cfn = make_cs(t1); layer(cf); if (((J0+0)&1)==0) crossl(); cf = cfn; }
    { float4 cfn = make_cs(t2); layer(cf); if (((J0+1)&1)==0) crossl(); cf = cfn; }
    { float4 cfn = make_cs(t3); layer(cf); if (((J0+2)&1)==0) crossl(); cf = cfn; }
    { float4 cfn = make_cs(t4); layer(cf); if (((J0+3)&1)==0) crossl(); cf = cfn; }
    { float4 cfn = make_cs(t5); layer(cf); if (((J0+4)&1)==0) crossl(); cf = cfn; }
    { float4 cfn = make_cs(t6); layer(cf); if (((J0+5)&1)==0) crossl(); cf = cfn; }
    { float4 cfn = make_cs(t7); layer(cf); if (((J0+6)&1)==0) crossl(); cf = cfn; }
    return cf;   // cs(theta[J0+127])
}

// ---------------- single launch: phases + grid barrier + combine ----------------
// blocks 0..127   : phase A (column c, layers 0..126) -> M1T[c][g]
// blocks 128..383 : phase B (basis g, layers 127..253 + fold) -> T2T[g][n]
// barrier (device-scope atomic arrival counter; ctr zeroed per call by memset)
// blocks 0..127   : combine column c -> out
__global__ __launch_bounds__(64) void fused_all(
    const float* __restrict__ theta_in,    // (128,)
    const float* __restrict__ theta_even,  // (255,128)
    const float* __restrict__ theta_out,   // (128,)
    float* __restrict__ out,               // (128,128)
    float2* __restrict__ M1T,              // [128][256]
    float2* __restrict__ T2T,              // [256][128]
    unsigned* __restrict__ ctr)
{
    const int bid = blockIdx.x;
    const int l = threadIdx.x;
    const float A = sqrtf(0.95f * 0.505f);
    const float B = sqrtf(0.95f * 0.495f);
    const float2* TL = (const float2*)theta_even + l;

    float2 v0 = make_float2(0.f, 0.f), v1 = v0, v2 = v0, v3 = v0;

    if (bid < 128) {
        const int c = bid;
        float s, co;
        __sincosf(theta_in[c], &s, &co);
        if (l == (c >> 1)) {
            float2 e0 = make_float2(A * co, A * s);
            float2 e1 = make_float2(-B * s, B * co);
            if (c & 1) { v2 = e0; v3 = e1; }
            else       { v0 = e0; v1 = e1; }
        }
        run127<0>(TL, l, v0, v1, v2, v3);
        float4* dst = (float4*)(M1T + (size_t)c * 256 + 4 * l);
        dst[0] = make_float4(v0.x, v0.y, v1.x, v1.y);
        dst[1] = make_float4(v2.x, v2.y, v3.x, v3.y);
    } else {
        const int g = bid - 128;
        if (l == (g >> 2)) {
            float2 one = make_float2(1.f, 0.f);
            int k = g & 3;
            if      (k == 0) v0 = one;
            else if (k == 1) v1 = one;
            else if (k == 2) v2 = one;
            else             v3 = one;
        }
        float4 cf = run127<127>(TL, l, v0, v1, v2, v3);   // cs(theta[254])
        float rx = cf.x * v0.x - cf.y * v0.y;
        float ry = cf.x * v0.y + cf.y * v0.x;
        float qx = cf.z * v2.x - cf.w * v2.y;
        float qy = cf.z * v2.y + cf.w * v2.x;
        float4 o;
        o.x = A * rx - B * v1.y;  o.y = A * ry + B * v1.x;   // row 2l
        o.z = A * qx - B * v3.y;  o.w = A * qy + B * v3.x;   // row 2l+1
        *(float4*)(T2T + (size_t)g * 128 + 2 * l) = o;
    }

    // ---- grid barrier: 384 single-wave blocks, all co-resident by capacity ----
    __threadfence();                         // release M1T/T2T (device scope)
    if (l == 0) {
        atomicAdd(ctr, 1u);                  // device-scope arrival
        while (__hip_atomic_load(ctr, __ATOMIC_RELAXED, __HIP_MEMORY_SCOPE_AGENT) < 384u)
            __builtin_amdgcn_s_sleep(2);
    }
    __threadfence();                         // acquire

    if (bid >= 128) return;

    // ---- combine for column c = bid: out[n][c] = Re(e^{i tho[n]} * sum_g T2[n][g]*M1[g][c]) ----
    const int c = bid;
    const float2* m1 = M1T + (size_t)c * 256;

    float2 a0e = make_float2(0.f, 0.f), a1e = a0e, a0o = a0e, a1o = a0e;
    #pragma unroll 4
    for (int g = 0; g < 256; g += 2) {
        float2 me = m1[g];                                            // wave-uniform
        float4 te = *(const float4*)(T2T + (size_t)g * 128 + 2 * l);  // coalesced
        a0e.x += te.x * me.x - te.y * me.y;  a0e.y += te.x * me.y + te.y * me.x;
        a1e.x += te.z * me.x - te.w * me.y;  a1e.y += te.z * me.y + te.w * me.x;
        float2 mo = m1[g + 1];
        float4 to = *(const float4*)(T2T + (size_t)(g + 1) * 128 + 2 * l);
        a0o.x += to.x * mo.x - to.y * mo.y;  a0o.y += to.x * mo.y + to.y * mo.x;
        a1o.x += to.z * mo.x - to.w * mo.y;  a1o.y += to.z * mo.y + to.w * mo.x;
    }
    float2 acc0 = make_float2(a0e.x + a0o.x, a0e.y + a0o.y);
    float2 acc1 = make_float2(a1e.x + a1o.x, a1e.y + a1o.y);

    float2 tho = ((const float2*)theta_out)[l];
    float s0, c0, s1, c1;
    __sincosf(tho.x, &s0, &c0);
    __sincosf(tho.y, &s1, &c1);
    out[(2 * l)     * NN + c] = c0 * acc0.x - s0 * acc0.y;
    out[(2 * l + 1) * NN + c] = c1 * acc1.x - s1 * acc1.y;
}

// ---------------- fallback: R15 single fused kernel (no ws needed, proven 29.9) ----------------
__global__ __launch_bounds__(64) void mesh_fused_kernel(
    const float* __restrict__ theta_in, const float* __restrict__ theta_even,
    const float* __restrict__ theta_out, float* __restrict__ out)
{
    const int c = blockIdx.x;
    const int l = threadIdx.x;
    const float A = sqrtf(0.95f * 0.505f);
    const float B = sqrtf(0.95f * 0.495f);
    const float2* TL = (const float2*)theta_even + l;

    float2 v0 = make_float2(0.f, 0.f), v1 = v0, v2 = v0, v3 = v0;
    {
        float s, co;
        __sincosf(theta_in[c], &s, &co);
        if (l == (c >> 1)) {
            float2 e0 = make_float2(A * co, A * s);
            float2 e1 = make_float2(-B * s, B * co);
            if (c & 1) { v2 = e0; v3 = e1; }
            else       { v0 = e0; v1 = e1; }
        }
    }
    run127<0>(TL, l, v0, v1, v2, v3);
    float4 cf = run127<127>(TL, l, v0, v1, v2, v3);
    float rx = cf.x * v0.x - cf.y * v0.y;
    float ry = cf.x * v0.y + cf.y * v0.x;
    float qx = cf.z * v2.x - cf.w * v2.y;
    float qy = cf.z * v2.y + cf.w * v2.x;
    float2 o0, o1;
    o0.x = A * rx - B * v1.y;  o0.y = A * ry + B * v1.x;
    o1.x = A * qx - B * v3.y;  o1.y = A * qy + B * v3.x;
    float2 tho = ((const float2*)theta_out)[l];
    float s0, c0, s1, c1;
    __sincosf(tho.x, &s0, &c0);
    __sincosf(tho.y, &s1, &c1);
    out[(2 * l)     * NN + c] = c0 * o0.x - s0 * o0.y;
    out[(2 * l + 1) * NN + c] = c1 * o1.x - s1 * o1.y;
}

extern "C" void kernel_launch(void* const* d_in, const int* in_sizes, int n_in,
                              void* d_out, int out_size, void* d_ws, size_t ws_size,
                              hipStream_t stream) {
    // Identify inputs by SIZE: theta_even is the unique large (32640) array;
    // the two 128-elem arrays keep relative order (theta_in before theta_out).
    int ev = 0;
    for (int i = 0; i < n_in; ++i) if (in_sizes[i] > 1000) ev = i;
    int a = -1, b = -1;
    for (int i = 0; i < n_in; ++i) {
        if (i == ev) continue;
        if (a < 0) a = i; else if (b < 0) b = i;
    }
    const float* th_in  = (const float*)d_in[a];
    const float* th_ev  = (const float*)d_in[ev];
    const float* th_out = (const float*)d_in[b];

    const size_t m1_bytes = (size_t)128 * 256 * sizeof(float2);   // 256 KB
    const size_t t2_bytes = (size_t)256 * 128 * sizeof(float2);   // 256 KB
    if (ws_size >= m1_bytes + t2_bytes + 64) {
        float2*   M1T = (float2*)d_ws;
        float2*   T2T = (float2*)((char*)d_ws + m1_bytes);
        unsigned* ctr = (unsigned*)((char*)d_ws + m1_bytes + t2_bytes);
        hipMemsetAsync(ctr, 0, sizeof(unsigned), stream);   // reset barrier each call
        fused_all<<<dim3(384), dim3(64), 0, stream>>>(
            th_in, th_ev, th_out, (float*)d_out, M1T, T2T, ctr);
    } else {
        mesh_fused_kernel<<<dim3(NN), dim3(64), 0, stream>>>(
            th_in, th_ev, th_out, (float*)d_out);
    }
}

// Round 18
// 27.782 us; speedup vs baseline: 2.9591x; 2.9591x over previous
//
#include <hip/hip_runtime.h>

#define NN 128   // modes

typedef float v2f __attribute__((ext_vector_type(2)));   // complex (re, im)

// ---- whole-wave lane shifts via DPP (wave_shl:1 / wave_shr:1), proven R9-R16 ----
__device__ __forceinline__ float wshl1(float x) {   // lane i <- lane i+1
    return __int_as_float(__builtin_amdgcn_update_dpp(
        __float_as_int(x), __float_as_int(x), 0x130, 0xf, 0xf, false));
}
__device__ __forceinline__ float wshr1(float x) {   // lane i <- lane i-1
    return __int_as_float(__builtin_amdgcn_update_dpp(
        __float_as_int(x), __float_as_int(x), 0x138, 0xf, 0xf, false));
}

// i * v  (multiply by imaginary unit): (re,im) -> (-im, re)
__device__ __forceinline__ v2f iswap(v2f v) { return (v2f){-v.y, v.x}; }

// (cos,sin) for the lane's two even rows of one layer: (c0,s0,c1,s1)
__device__ __forceinline__ float4 make_cs(v2f th) {
    float s0, c0, s1, c1;
    __sincosf(th.x, &s0, &c0);
    __sincosf(th.y, &s1, &c1);
    return make_float4(c0, s0, c1, s1);
}

// ---------------- single fused kernel (R15 structure, packed-f32 math) ----------------
// One wave per column c (128 blocks). Lane l holds rows 4l..4l+3 (4 complex).
// Static 8-deep theta ring (loads write consume slots directly); sincos one
// layer ahead of the state chain; cross-lane via whole-wave DPP; complex math
// as 2-wide vector ops -> v_pk_mul_f32 / v_pk_fma_f32.
__global__ __launch_bounds__(64) void mesh_fused_kernel(
    const float* __restrict__ theta_in,    // (128,)
    const float* __restrict__ theta_even,  // (255,128)
    const float* __restrict__ theta_out,   // (128,)
    float* __restrict__ out)               // (128,128) f32 = Re(arch)
{
    const int c = blockIdx.x;
    const int l = threadIdx.x;

    const float A  = sqrtf(0.95f * 0.505f);
    const float B  = sqrtf(0.95f * 0.495f);
    const float C2 = sqrtf(0.98f * 0.01f);
    const float S2 = sqrtf(0.98f * 0.99f);

    // branchless corner coeffs: row 0 (l==0, slot v0), row 255 (l==63, slot v3)
    const float ec0 = (l == 0)  ? S2 : C2, es0 = (l == 0)  ? 0.f : S2;
    const float ec3 = (l == 63) ? S2 : C2, es3 = (l == 63) ? 0.f : S2;

    // theta ring: lane l needs theta_even[j*128 + 2l .. 2l+1] = v2f at j*64+l
    const v2f* TL = (const v2f*)theta_even + l;
    v2f t0 = TL[0*64], t1 = TL[1*64], t2 = TL[2*64], t3 = TL[3*64],
        t4 = TL[4*64], t5 = TL[5*64], t6 = TL[6*64], t7 = TL[7*64];

    // init: column c after MMI_IN -> rows 2c: A e^{i th}, 2c+1: iB e^{i th}
    v2f v0 = (v2f){0.f, 0.f}, v1 = v0, v2 = v0, v3 = v0;
    {
        float s, co;
        __sincosf(theta_in[c], &s, &co);
        v2f e0 = (v2f){A * co, A * s};
        v2f e1 = (v2f){-B * s, B * co};
        if (l == (c >> 1)) {
            if (c & 1) { v2 = e0; v3 = e1; }
            else       { v0 = e0; v1 = e1; }
        }
    }

    // rotate-then-mix layer: t = (c0,s0,c1,s1). All packed complex ops.
    auto layer = [&](float4 t) {
        v2f r = t.x * v0 + t.y * iswap(v0);    // e^{i th} * v0
        v2f q = t.z * v2 + t.w * iswap(v2);    // e^{i th'} * v2
        v2f n0 = A * r  + B * iswap(v1);
        v2f n1 = A * v1 + B * iswap(r);
        v2f n2 = A * q  + B * iswap(v3);
        v2f n3 = A * v3 + B * iswap(q);
        v0 = n0; v1 = n1; v2 = n2; v3 = n3;
    };
    auto crossl = [&]() {
        v2f nxt = (v2f){wshl1(v0.x), wshl1(v0.y)};   // lane l+1's v0
        v2f prv = (v2f){wshr1(v3.x), wshr1(v3.y)};   // lane l-1's v3
        v2f m0 = ec0 * v0 + es0 * iswap(prv);
        v2f m3 = ec3 * v3 + es3 * iswap(nxt);
        v2f m1 = C2 * v1 + S2 * iswap(v2);
        v2f m2 = C2 * v2 + S2 * iswap(v1);
        v0 = m0; v1 = m1; v2 = m2; v3 = m3;
    };

    float4 cf = make_cs(t0);   // layer 0 coefficients

    // 31 batches of 8: layers 0..247. Slot k reloaded with theta[j8+8+k]
    // (only slot 7 can exceed 254: clamp). Load->use distance = 7 steps.
    for (int j8 = 0; j8 < 248; j8 += 8) {
        { t0 = TL[(j8+ 8)*64]; float4 cfn = make_cs(t1); layer(cf); crossl(); cf = cfn; }
        { t1 = TL[(j8+ 9)*64]; float4 cfn = make_cs(t2); layer(cf);           cf = cfn; }
        { t2 = TL[(j8+10)*64]; float4 cfn = make_cs(t3); layer(cf); crossl(); cf = cfn; }
        { t3 = TL[(j8+11)*64]; float4 cfn = make_cs(t4); layer(cf);           cf = cfn; }
        { t4 = TL[(j8+12)*64]; float4 cfn = make_cs(t5); layer(cf); crossl(); cf = cfn; }
        { t5 = TL[(j8+13)*64]; float4 cfn = make_cs(t6); layer(cf);           cf = cfn; }
        { t6 = TL[(j8+14)*64]; float4 cfn = make_cs(t7); layer(cf); crossl(); cf = cfn; }
        { int i7 = j8 + 15; if (i7 > 254) i7 = 254;
          t7 = TL[i7*64];      float4 cfn = make_cs(t0); layer(cf);           cf = cfn; }
    }
    // tail: layers 248..253 (t0..t6 hold theta[248..254])
    { float4 cfn = make_cs(t1); layer(cf); crossl(); cf = cfn; }   // 248
    { float4 cfn = make_cs(t2); layer(cf);           cf = cfn; }   // 249
    { float4 cfn = make_cs(t3); layer(cf); crossl(); cf = cfn; }   // 250
    { float4 cfn = make_cs(t4); layer(cf);           cf = cfn; }   // 251
    { float4 cfn = make_cs(t5); layer(cf); crossl(); cf = cfn; }   // 252
    { float4 cfn = make_cs(t6); layer(cf);           cf = cfn; }   // 253

    // cf = cs(theta[254]): final diag + MMI_OUT fold -> rows 2l, 2l+1
    v2f r254 = cf.x * v0 + cf.y * iswap(v0);
    v2f q254 = cf.z * v2 + cf.w * iswap(v2);
    v2f o0 = A * r254 + B * iswap(v1);
    v2f o1 = A * q254 + B * iswap(v3);

    // diag(d_out) rotation, keep real part
    v2f tho = ((const v2f*)theta_out)[l];
    float s0, c0, s1, c1;
    __sincosf(tho.x, &s0, &c0);
    __sincosf(tho.y, &s1, &c1);
    out[(2 * l)     * NN + c] = c0 * o0.x - s0 * o0.y;
    out[(2 * l + 1) * NN + c] = c1 * o1.x - s1 * o1.y;
}

extern "C" void kernel_launch(void* const* d_in, const int* in_sizes, int n_in,
                              void* d_out, int out_size, void* d_ws, size_t ws_size,
                              hipStream_t stream) {
    // Identify inputs by SIZE: theta_even is the unique large (32640) array;
    // the two 128-elem arrays keep relative order (theta_in before theta_out).
    int ev = 0;
    for (int i = 0; i < n_in; ++i) if (in_sizes[i] > 1000) ev = i;
    int a = -1, b = -1;
    for (int i = 0; i < n_in; ++i) {
        if (i == ev) continue;
        if (a < 0) a = i; else if (b < 0) b = i;
    }
    const float* th_in  = (const float*)d_in[a];
    const float* th_ev  = (const float*)d_in[ev];
    const float* th_out = (const float*)d_in[b];
    mesh_fused_kernel<<<dim3(NN), dim3(64), 0, stream>>>(
        th_in, th_ev, th_out, (float*)d_out);
}